// Round 10
// baseline (250.897 us; speedup 1.0000x reference)
//
#include <hip/hip_runtime.h>

#define B_TOT 16384
#define DIMN  4096
#define EPSF  1e-10f

// ws layout (floats): absamp[16384*8] at 0, blocksum[1024*3] at 131072
#define ABS_OFF 0u
#define MET_OFF 131072u

__device__ __forceinline__ void normalize8(float* rr, float* ii) {
  float n2 = 0.f;
#pragma unroll
  for (int q = 0; q < 8; q++) n2 += rr[q] * rr[q] + ii[q] * ii[q];
  float n = sqrtf(n2);
  if (n < EPSF) {
#pragma unroll
    for (int q = 0; q < 8; q++) { rr[q] = 0.f; ii[q] = 0.f; }
    rr[0] = 1.f;
  } else {
    float inv = 1.f / n;
#pragma unroll
    for (int q = 0; q < 8; q++) { rr[q] *= inv; ii[q] *= inv; }
  }
}

#define DOT4(a, wA, p)                                                     \
  fmaf((a).x, (wA).x, fmaf((a).y, (wA).y, fmaf((a).z, (wA).z,              \
  fmaf((a).w, (wA).w, (p)))))

// K1: enc GEMM + evolve + metrics. 1024 blocks x 256 thr (4 waves).
// Block = 16 rows; wave w owns features {4w..4w+3}; lane = (row l&15, K-quarter l>>4).
// x double-buffered in LDS (stride 260, 2-way = free); W per-lane from L2.
// acc[4] + 4 staging regs -> ~50 VGPR, no spill. One barrier per chunk.
__global__ __launch_bounds__(256) void k_enc(
    const float* __restrict__ x, const float* __restrict__ wenc,
    const float* __restrict__ benc, const float* __restrict__ phase,
    const float* __restrict__ disorder, float* __restrict__ absamp,
    float* __restrict__ blocksum) {
  __shared__ float xt[2][16 * 260];            // 2 x 16.6 KB
  __shared__ float encL[16 * 17];
  const int t = threadIdx.x;
  const int l = t & 63;
  const int w = t >> 6;                         // wave id 0..3 (= feature group)
  const int r0 = blockIdx.x * 16;
  const int col4 = (t & 63) * 4;                // 0..252, float4 column in chunk
  const int rloc = l & 15;                      // row within block
  const int q = l >> 4;                         // K-quarter 0..3

  float acc[4] = {0.f, 0.f, 0.f, 0.f};
  float4 rg0, rg1, rg2, rg3;

  // prologue: stage chunk 0 (rows p*4+w per pass p)
  rg0 = *reinterpret_cast<const float4*>(x + (size_t)(r0 + 0 * 4 + w) * DIMN + col4);
  rg1 = *reinterpret_cast<const float4*>(x + (size_t)(r0 + 1 * 4 + w) * DIMN + col4);
  rg2 = *reinterpret_cast<const float4*>(x + (size_t)(r0 + 2 * 4 + w) * DIMN + col4);
  rg3 = *reinterpret_cast<const float4*>(x + (size_t)(r0 + 3 * 4 + w) * DIMN + col4);
  *reinterpret_cast<float4*>(&xt[0][(0 * 4 + w) * 260 + col4]) = rg0;
  *reinterpret_cast<float4*>(&xt[0][(1 * 4 + w) * 260 + col4]) = rg1;
  *reinterpret_cast<float4*>(&xt[0][(2 * 4 + w) * 260 + col4]) = rg2;
  *reinterpret_cast<float4*>(&xt[0][(3 * 4 + w) * 260 + col4]) = rg3;

  for (int c = 0; c < 16; ++c) {               // K chunks of 256
    const int cur = c & 1;
    __syncthreads();                           // buf[cur] staged; prev compute done
    if (c < 15) {                              // issue next-chunk loads (in flight
      const size_t co = (size_t)(c + 1) * 256 + col4;           //  during compute)
      rg0 = *reinterpret_cast<const float4*>(x + (size_t)(r0 + 0 * 4 + w) * DIMN + co);
      rg1 = *reinterpret_cast<const float4*>(x + (size_t)(r0 + 1 * 4 + w) * DIMN + co);
      rg2 = *reinterpret_cast<const float4*>(x + (size_t)(r0 + 2 * 4 + w) * DIMN + co);
      rg3 = *reinterpret_cast<const float4*>(x + (size_t)(r0 + 3 * 4 + w) * DIMN + co);
    }
    const float* __restrict__ xb = &xt[cur][rloc * 260 + q * 64];
    const float* __restrict__ wb = wenc + (size_t)(w * 4) * DIMN + c * 256 + q * 64;
#pragma unroll 4
    for (int i = 0; i < 16; ++i) {
      float4 xv = *reinterpret_cast<const float4*>(xb + i * 4);
      float4 w0 = *reinterpret_cast<const float4*>(wb + i * 4);
      float4 w1 = *reinterpret_cast<const float4*>(wb + DIMN + i * 4);
      float4 w2 = *reinterpret_cast<const float4*>(wb + 2 * DIMN + i * 4);
      float4 w3 = *reinterpret_cast<const float4*>(wb + 3 * DIMN + i * 4);
      acc[0] = DOT4(xv, w0, acc[0]);
      acc[1] = DOT4(xv, w1, acc[1]);
      acc[2] = DOT4(xv, w2, acc[2]);
      acc[3] = DOT4(xv, w3, acc[3]);
    }
    if (c < 15) {                              // write prefetched regs -> other buf
      *reinterpret_cast<float4*>(&xt[cur ^ 1][(0 * 4 + w) * 260 + col4]) = rg0;
      *reinterpret_cast<float4*>(&xt[cur ^ 1][(1 * 4 + w) * 260 + col4]) = rg1;
      *reinterpret_cast<float4*>(&xt[cur ^ 1][(2 * 4 + w) * 260 + col4]) = rg2;
      *reinterpret_cast<float4*>(&xt[cur ^ 1][(3 * 4 + w) * 260 + col4]) = rg3;
    }
  }

  // fold K-quarters: lanes l, l^16, l^32 hold partials of same (row, features)
#pragma unroll
  for (int j = 0; j < 4; ++j) {
    acc[j] += __shfl_xor(acc[j], 16);
    acc[j] += __shfl_xor(acc[j], 32);
  }
  if (l < 16) {
#pragma unroll
    for (int j = 0; j < 4; ++j) encL[l * 17 + w * 4 + j] = acc[j];
  }
  __syncthreads();

  if (t < 16) {                                // one thread per row: evolve+metrics
    const int r = r0 + t;
    float e[16];
#pragma unroll
    for (int k = 0; k < 16; k++) e[k] = tanhf(encL[t * 17 + k] + benc[k]);

    float re[8], im[8];
#pragma unroll
    for (int q2 = 0; q2 < 8; q2++) {
      float ph = 0.1f * phase[q2];
      float cc = cosf(ph), ss = sinf(ph);
      re[q2] = e[q2] * cc - e[8 + q2] * ss + 0.017677669529663688f;  // +0.05/sqrt(8)
      im[q2] = e[q2] * ss + e[8 + q2] * cc;
    }
    normalize8(re, im);

    float dd0 = disorder[0], dd1 = disorder[1], dd2 = disorder[2];
    float hz[8];
#pragma unroll
    for (int i = 0; i < 8; i++)
      hz[i] = ((i & 4) ? -dd0 : dd0) + ((i & 2) ? -dd1 : dd1) + ((i & 1) ? -dd2 : dd2);

#pragma unroll
    for (int step = 0; step < 2; step++) {
      float tt = 0.02f * (float)r + 0.01f * (float)step;
      float drive = 0.5f + 0.2f * sinf(1.61803398874989485f * tt);
      float nr[8], ni[8];
#pragma unroll
      for (int j = 0; j < 8; j++) {
        float hr = drive * (re[j ^ 1] + re[j ^ 2] + re[j ^ 4]) + hz[j] * re[j];
        float hi = drive * (im[j ^ 1] + im[j ^ 2] + im[j ^ 4]) + hz[j] * im[j];
        nr[j] = re[j] + 1e-4f * hi;            // amps - 1j*1e-4*Ha
        ni[j] = im[j] - 1e-4f * hr;
      }
      normalize8(nr, ni);
#pragma unroll
      for (int j = 0; j < 8; j++) { re[j] = nr[j]; im[j] = ni[j]; }
    }

    float tr = 0.f, s2 = 0.f;
    float ab[8];
#pragma unroll
    for (int q2 = 0; q2 < 8; q2++) {
      float a2 = re[q2] * re[q2] + im[q2] * im[q2];
      tr += a2; s2 += a2 * a2;
      ab[q2] = sqrtf(a2);
    }
    *reinterpret_cast<float4*>(absamp + (size_t)r * 8) =
        make_float4(ab[0], ab[1], ab[2], ab[3]);
    *reinterpret_cast<float4*>(absamp + (size_t)r * 8 + 4) =
        make_float4(ab[4], ab[5], ab[6], ab[7]);

    float trp = tr + EPSF;
    float purity = tr * tr / (trp * trp);
    float coh = sqrtf(fmaxf(tr * tr - s2, 0.f)) / trp;
    float lam = fminf(fmaxf(tr / trp, EPSF), 1.f);   // rho rank-1
    float denom = lam + 8.f * EPSF;
    float e1 = lam / denom, er = EPSF / denom;
    float ent = -(e1 * log2f(e1 + EPSF) + 7.f * er * log2f(er + EPSF));

    float sp = purity, sc = coh, sh = ent;
#pragma unroll
    for (int off = 8; off > 0; off >>= 1) {    // 16 active lanes
      sp += __shfl_xor(sp, off);
      sc += __shfl_xor(sc, off);
      sh += __shfl_xor(sh, off);
    }
    if (t == 0) {
      blocksum[blockIdx.x * 3 + 0] = sp;
      blocksum[blockIdx.x * 3 + 1] = sc;
      blocksum[blockIdx.x * 3 + 2] = sh;
    }
  }
}

// K2: dedicated decode (clean clustered writes).
__global__ __launch_bounds__(256) void k_out(const float* __restrict__ absamp,
                                             const float* __restrict__ wdec,
                                             const float* __restrict__ bdec,
                                             float* __restrict__ out) {
  const int t = threadIdx.x;
  const int r0 = blockIdx.x * 64;
  const int c0 = blockIdx.y * 1024 + t * 4;
  float wv[4][8];
#pragma unroll
  for (int j = 0; j < 4; j++) {
    float4 a = *reinterpret_cast<const float4*>(wdec + (size_t)(c0 + j) * 8);
    float4 b = *reinterpret_cast<const float4*>(wdec + (size_t)(c0 + j) * 8 + 4);
    wv[j][0] = a.x; wv[j][1] = a.y; wv[j][2] = a.z; wv[j][3] = a.w;
    wv[j][4] = b.x; wv[j][5] = b.y; wv[j][6] = b.z; wv[j][7] = b.w;
  }
  float4 bd = *reinterpret_cast<const float4*>(bdec + c0);

  __shared__ float as_[512];                    // 64 rows x 8 q
  float2 av = *reinterpret_cast<const float2*>(absamp + (size_t)r0 * 8 + t * 2);
  as_[t * 2] = av.x; as_[t * 2 + 1] = av.y;
  __syncthreads();

  for (int r = 0; r < 64; r++) {
    float o0 = bd.x, o1 = bd.y, o2 = bd.z, o3 = bd.w;
#pragma unroll
    for (int q = 0; q < 8; q++) {
      float aq = as_[r * 8 + q];                // uniform -> broadcast
      o0 = fmaf(aq, wv[0][q], o0);
      o1 = fmaf(aq, wv[1][q], o1);
      o2 = fmaf(aq, wv[2][q], o2);
      o3 = fmaf(aq, wv[3][q], o3);
    }
    *reinterpret_cast<float4*>(out + (size_t)(r0 + r) * DIMN + c0) =
        make_float4(o0, o1, o2, o3);
  }
}

// K3: finalize metric means (1024 block partials)
__global__ void k_final(const float* __restrict__ blocksum,
                        float* __restrict__ out) {
  const int t = threadIdx.x;
  float s0 = 0.f, s1 = 0.f, s2 = 0.f;
  for (int b = t; b < 1024; b += 64) {
    s0 += blocksum[b * 3 + 0];
    s1 += blocksum[b * 3 + 1];
    s2 += blocksum[b * 3 + 2];
  }
#pragma unroll
  for (int off = 32; off > 0; off >>= 1) {
    s0 += __shfl_down(s0, off);
    s1 += __shfl_down(s1, off);
    s2 += __shfl_down(s2, off);
  }
  if (t == 0) {
    out[(size_t)B_TOT * DIMN + 0] = s0 / 16384.f;
    out[(size_t)B_TOT * DIMN + 1] = s1 / 16384.f;
    out[(size_t)B_TOT * DIMN + 2] = s2 / 16384.f;
  }
}

extern "C" void kernel_launch(void* const* d_in, const int* in_sizes, int n_in,
                              void* d_out, int out_size, void* d_ws, size_t ws_size,
                              hipStream_t stream) {
  const float *x = nullptr, *wenc = nullptr, *benc = nullptr, *phase = nullptr,
              *wdec = nullptr, *bdec = nullptr, *dis = nullptr;
  for (int i = 0; i < n_in; i++) {
    switch (in_sizes[i]) {
      case 67108864: x = (const float*)d_in[i]; break;      // 16384*4096
      case 65536:    wenc = (const float*)d_in[i]; break;   // 16*4096
      case 16:       benc = (const float*)d_in[i]; break;
      case 8:        phase = (const float*)d_in[i]; break;
      case 32768:    wdec = (const float*)d_in[i]; break;   // 4096*8
      case 4096:     bdec = (const float*)d_in[i]; break;
      case 3:        dis = (const float*)d_in[i]; break;
      default: break;
    }
  }

  float* ws = (float*)d_ws;
  float* absamp = ws + ABS_OFF;
  float* bsum   = ws + MET_OFF;
  float* out = (float*)d_out;

  hipLaunchKernelGGL(k_enc, dim3(1024), dim3(256), 0, stream,
                     x, wenc, benc, phase, dis, absamp, bsum);
  hipLaunchKernelGGL(k_out, dim3(256, 4), dim3(256), 0, stream,
                     absamp, wdec, bdec, out);
  hipLaunchKernelGGL(k_final, dim3(1), dim3(64), 0, stream, bsum, out);
}

// Round 11
// 197.605 us; speedup vs baseline: 1.2697x; 1.2697x over previous
//
#include <hip/hip_runtime.h>

#define B_TOT 16384
#define DIMN  4096
#define EPSF  1e-10f

// ws layout (floats): absamp[16384*8] at 0, blocksum[256*3] at 131072
#define ABS_OFF 0u
#define MET_OFF 131072u

#define RS  64     // rows per block
#define CH  64     // cols per chunk
#define NCH 64     // chunks
#define XS  68     // x LDS row stride
#define WSTR 68    // w LDS row stride

__device__ __forceinline__ void normalize8(float* rr, float* ii) {
  float n2 = 0.f;
#pragma unroll
  for (int q = 0; q < 8; q++) n2 += rr[q] * rr[q] + ii[q] * ii[q];
  float n = sqrtf(n2);
  if (n < EPSF) {
#pragma unroll
    for (int q = 0; q < 8; q++) { rr[q] = 0.f; ii[q] = 0.f; }
    rr[0] = 1.f;
  } else {
    float inv = 1.f / n;
#pragma unroll
    for (int q = 0; q < 8; q++) { rr[q] *= inv; ii[q] *= inv; }
  }
}

#define DOT4(a, wA, p)                                                     \
  fmaf((a).x, (wA).x, fmaf((a).y, (wA).y, fmaf((a).z, (wA).z,              \
  fmaf((a).w, (wA).w, (p)))))

// K1: enc GEMM (4x4 register outer product, x+W in LDS) + evolve + metrics.
// 256 blocks x 512 thr (8 waves). Block = 64 rows. Wave w = K-slice
// [w*8, w*8+8) per 64-col chunk. Lane: rho=l&15 -> rows 4rho..+3,
// phi=l>>4 -> feats 4phi..+3. acc[4][4]. 1:8 LDS:FMA instr ratio.
__global__ __launch_bounds__(512) void k_enc(
    const float* __restrict__ x, const float* __restrict__ wenc,
    const float* __restrict__ benc, const float* __restrict__ phase,
    const float* __restrict__ disorder, float* __restrict__ absamp,
    float* __restrict__ blocksum) {
  __shared__ float lds[2 * RS * XS + 2 * 16 * WSTR];   // 10880 f = 43.5 KB
  float* const xt0 = lds;
  float* const xt1 = lds + RS * XS;
  float* const wt0 = lds + 2 * RS * XS;
  float* const wt1 = lds + 2 * RS * XS + 16 * WSTR;

  const int t = threadIdx.x;            // 0..511
  const int l = t & 63;
  const int w = t >> 6;                 // K-eighth 0..7
  const int r0 = blockIdx.x * RS;
  const int rho = l & 15;
  const int phi = l >> 4;

  float acc[4][4];
#pragma unroll
  for (int r = 0; r < 4; r++)
#pragma unroll
    for (int f = 0; f < 4; f++) acc[r][f] = 0.f;

  // staging slots: x: v = j*512+t -> row=v>>4, col4=(v&15)*4 (j=0,1)
  const int xrow0 = t >> 4, xc0 = (t & 15) * 4;
  const int xrow1 = 32 + (t >> 4), xc1 = (t & 15) * 4;
  const int wfr = t >> 4, wc = (t & 15) * 4;   // valid for t<256

  // prologue: load + stage chunk 0 into buf0
  float4 xg0 = *reinterpret_cast<const float4*>(x + (size_t)(r0 + xrow0) * DIMN + xc0);
  float4 xg1 = *reinterpret_cast<const float4*>(x + (size_t)(r0 + xrow1) * DIMN + xc1);
  float4 wg;
  if (t < 256) wg = *reinterpret_cast<const float4*>(wenc + (size_t)wfr * DIMN + wc);
  *reinterpret_cast<float4*>(&xt0[xrow0 * XS + xc0]) = xg0;
  *reinterpret_cast<float4*>(&xt1[0] + (xrow1 - 32) * XS + xc1 - (RS - 32) * XS) =
      xg1;  // placeholder avoided below
  // (rewrite cleanly)
  *reinterpret_cast<float4*>(&xt0[xrow1 * XS + xc1]) = xg1;
  if (t < 256) *reinterpret_cast<float4*>(&wt0[wfr * WSTR + wc]) = wg;

  for (int c = 0; c < NCH; ++c) {
    const int cur = c & 1;
    __syncthreads();                     // buf[cur] staged, prev compute done
    if (c + 1 < NCH) {                   // issue next-chunk loads
      const size_t co = (size_t)(c + 1) * CH;
      xg0 = *reinterpret_cast<const float4*>(x + (size_t)(r0 + xrow0) * DIMN + co + xc0);
      xg1 = *reinterpret_cast<const float4*>(x + (size_t)(r0 + xrow1) * DIMN + co + xc1);
      if (t < 256)
        wg = *reinterpret_cast<const float4*>(wenc + (size_t)wfr * DIMN + co + wc);
    }
    const float* __restrict__ xb = cur ? xt1 : xt0;
    const float* __restrict__ wb = cur ? wt1 : wt0;
#pragma unroll
    for (int s = 0; s < 2; ++s) {
      const int col = w * 8 + s * 4;
      float4 xr0 = *reinterpret_cast<const float4*>(&xb[(4 * rho + 0) * XS + col]);
      float4 xr1 = *reinterpret_cast<const float4*>(&xb[(4 * rho + 1) * XS + col]);
      float4 xr2 = *reinterpret_cast<const float4*>(&xb[(4 * rho + 2) * XS + col]);
      float4 xr3 = *reinterpret_cast<const float4*>(&xb[(4 * rho + 3) * XS + col]);
      float4 wf0 = *reinterpret_cast<const float4*>(&wb[(4 * phi + 0) * WSTR + col]);
      float4 wf1 = *reinterpret_cast<const float4*>(&wb[(4 * phi + 1) * WSTR + col]);
      float4 wf2 = *reinterpret_cast<const float4*>(&wb[(4 * phi + 2) * WSTR + col]);
      float4 wf3 = *reinterpret_cast<const float4*>(&wb[(4 * phi + 3) * WSTR + col]);
      acc[0][0] = DOT4(xr0, wf0, acc[0][0]);
      acc[0][1] = DOT4(xr0, wf1, acc[0][1]);
      acc[0][2] = DOT4(xr0, wf2, acc[0][2]);
      acc[0][3] = DOT4(xr0, wf3, acc[0][3]);
      acc[1][0] = DOT4(xr1, wf0, acc[1][0]);
      acc[1][1] = DOT4(xr1, wf1, acc[1][1]);
      acc[1][2] = DOT4(xr1, wf2, acc[1][2]);
      acc[1][3] = DOT4(xr1, wf3, acc[1][3]);
      acc[2][0] = DOT4(xr2, wf0, acc[2][0]);
      acc[2][1] = DOT4(xr2, wf1, acc[2][1]);
      acc[2][2] = DOT4(xr2, wf2, acc[2][2]);
      acc[2][3] = DOT4(xr2, wf3, acc[2][3]);
      acc[3][0] = DOT4(xr3, wf0, acc[3][0]);
      acc[3][1] = DOT4(xr3, wf1, acc[3][1]);
      acc[3][2] = DOT4(xr3, wf2, acc[3][2]);
      acc[3][3] = DOT4(xr3, wf3, acc[3][3]);
    }
    if (c + 1 < NCH) {                   // write prefetched regs -> other buf
      float* xo = cur ? xt0 : xt1;
      float* wo = cur ? wt0 : wt1;
      *reinterpret_cast<float4*>(&xo[xrow0 * XS + xc0]) = xg0;
      *reinterpret_cast<float4*>(&xo[xrow1 * XS + xc1]) = xg1;
      if (t < 256) *reinterpret_cast<float4*>(&wo[wfr * WSTR + wc]) = wg;
    }
  }
  __syncthreads();                       // all xt/wt reads done; reuse lds

  // partials: red[(row*16+feat)*8 + w] in lds[0..8191]
#pragma unroll
  for (int r = 0; r < 4; ++r)
#pragma unroll
    for (int f = 0; f < 4; ++f)
      lds[(((4 * rho + r) * 16) + (4 * phi + f)) * 8 + w] = acc[r][f];
  __syncthreads();

  // reduce 8 partials -> enc; encL at lds[8704 + row*17 + feat] (disjoint)
  float* const encL = lds + 8704;
  {
    const int o0 = t * 2, o1 = t * 2 + 1;
    float4 a0 = *reinterpret_cast<const float4*>(&lds[o0 * 8]);
    float4 b0 = *reinterpret_cast<const float4*>(&lds[o0 * 8 + 4]);
    float4 a1 = *reinterpret_cast<const float4*>(&lds[o1 * 8]);
    float4 b1 = *reinterpret_cast<const float4*>(&lds[o1 * 8 + 4]);
    float s0 = ((a0.x + a0.y) + (a0.z + a0.w)) + ((b0.x + b0.y) + (b0.z + b0.w));
    float s1 = ((a1.x + a1.y) + (a1.z + a1.w)) + ((b1.x + b1.y) + (b1.z + b1.w));
    encL[(o0 >> 4) * 17 + (o0 & 15)] = s0;
    encL[(o1 >> 4) * 17 + (o1 & 15)] = s1;
  }
  __syncthreads();

  if (t < 64) {                          // one thread per row: evolve + metrics
    const int r = r0 + t;
    float e[16];
#pragma unroll
    for (int k = 0; k < 16; k++) e[k] = tanhf(encL[t * 17 + k] + benc[k]);

    float re[8], im[8];
#pragma unroll
    for (int q = 0; q < 8; q++) {
      float ph = 0.1f * phase[q];
      float cc = cosf(ph), ss = sinf(ph);
      re[q] = e[q] * cc - e[8 + q] * ss + 0.017677669529663688f;  // +0.05/sqrt(8)
      im[q] = e[q] * ss + e[8 + q] * cc;
    }
    normalize8(re, im);

    float dd0 = disorder[0], dd1 = disorder[1], dd2 = disorder[2];
    float hz[8];
#pragma unroll
    for (int i = 0; i < 8; i++)
      hz[i] = ((i & 4) ? -dd0 : dd0) + ((i & 2) ? -dd1 : dd1) + ((i & 1) ? -dd2 : dd2);

#pragma unroll
    for (int step = 0; step < 2; step++) {
      float tt = 0.02f * (float)r + 0.01f * (float)step;
      float drive = 0.5f + 0.2f * sinf(1.61803398874989485f * tt);
      float nr[8], ni[8];
#pragma unroll
      for (int j = 0; j < 8; j++) {
        float hr = drive * (re[j ^ 1] + re[j ^ 2] + re[j ^ 4]) + hz[j] * re[j];
        float hi = drive * (im[j ^ 1] + im[j ^ 2] + im[j ^ 4]) + hz[j] * im[j];
        nr[j] = re[j] + 1e-4f * hi;      // amps - 1j*1e-4*Ha
        ni[j] = im[j] - 1e-4f * hr;
      }
      normalize8(nr, ni);
#pragma unroll
      for (int j = 0; j < 8; j++) { re[j] = nr[j]; im[j] = ni[j]; }
    }

    float tr = 0.f, s2 = 0.f;
    float ab[8];
#pragma unroll
    for (int q = 0; q < 8; q++) {
      float a2 = re[q] * re[q] + im[q] * im[q];
      tr += a2; s2 += a2 * a2;
      ab[q] = sqrtf(a2);
    }
    *reinterpret_cast<float4*>(absamp + (size_t)r * 8) =
        make_float4(ab[0], ab[1], ab[2], ab[3]);
    *reinterpret_cast<float4*>(absamp + (size_t)r * 8 + 4) =
        make_float4(ab[4], ab[5], ab[6], ab[7]);

    float trp = tr + EPSF;
    float purity = tr * tr / (trp * trp);
    float coh = sqrtf(fmaxf(tr * tr - s2, 0.f)) / trp;
    float lam = fminf(fmaxf(tr / trp, EPSF), 1.f);   // rho rank-1
    float denom = lam + 8.f * EPSF;
    float e1 = lam / denom, er = EPSF / denom;
    float ent = -(e1 * log2f(e1 + EPSF) + 7.f * er * log2f(er + EPSF));

    float sp = purity, sc = coh, sh = ent;
#pragma unroll
    for (int off = 32; off > 0; off >>= 1) {
      sp += __shfl_xor(sp, off);
      sc += __shfl_xor(sc, off);
      sh += __shfl_xor(sh, off);
    }
    if (t == 0) {
      blocksum[blockIdx.x * 3 + 0] = sp;
      blocksum[blockIdx.x * 3 + 1] = sc;
      blocksum[blockIdx.x * 3 + 2] = sh;
    }
  }
}

// K2: dedicated decode (clean clustered writes).
__global__ __launch_bounds__(256) void k_out(const float* __restrict__ absamp,
                                             const float* __restrict__ wdec,
                                             const float* __restrict__ bdec,
                                             float* __restrict__ out) {
  const int t = threadIdx.x;
  const int r0 = blockIdx.x * 64;
  const int c0 = blockIdx.y * 1024 + t * 4;
  float wv[4][8];
#pragma unroll
  for (int j = 0; j < 4; j++) {
    float4 a = *reinterpret_cast<const float4*>(wdec + (size_t)(c0 + j) * 8);
    float4 b = *reinterpret_cast<const float4*>(wdec + (size_t)(c0 + j) * 8 + 4);
    wv[j][0] = a.x; wv[j][1] = a.y; wv[j][2] = a.z; wv[j][3] = a.w;
    wv[j][4] = b.x; wv[j][5] = b.y; wv[j][6] = b.z; wv[j][7] = b.w;
  }
  float4 bd = *reinterpret_cast<const float4*>(bdec + c0);

  __shared__ float as_[512];                    // 64 rows x 8 q
  float2 av = *reinterpret_cast<const float2*>(absamp + (size_t)r0 * 8 + t * 2);
  as_[t * 2] = av.x; as_[t * 2 + 1] = av.y;
  __syncthreads();

  for (int r = 0; r < 64; r++) {
    float o0 = bd.x, o1 = bd.y, o2 = bd.z, o3 = bd.w;
#pragma unroll
    for (int q = 0; q < 8; q++) {
      float aq = as_[r * 8 + q];                // uniform -> broadcast
      o0 = fmaf(aq, wv[0][q], o0);
      o1 = fmaf(aq, wv[1][q], o1);
      o2 = fmaf(aq, wv[2][q], o2);
      o3 = fmaf(aq, wv[3][q], o3);
    }
    *reinterpret_cast<float4*>(out + (size_t)(r0 + r) * DIMN + c0) =
        make_float4(o0, o1, o2, o3);
  }
}

// K3: finalize metric means (256 block partials)
__global__ void k_final(const float* __restrict__ blocksum,
                        float* __restrict__ out) {
  const int t = threadIdx.x;
  float s0 = 0.f, s1 = 0.f, s2 = 0.f;
  for (int b = t; b < 256; b += 64) {
    s0 += blocksum[b * 3 + 0];
    s1 += blocksum[b * 3 + 1];
    s2 += blocksum[b * 3 + 2];
  }
#pragma unroll
  for (int off = 32; off > 0; off >>= 1) {
    s0 += __shfl_down(s0, off);
    s1 += __shfl_down(s1, off);
    s2 += __shfl_down(s2, off);
  }
  if (t == 0) {
    out[(size_t)B_TOT * DIMN + 0] = s0 / 16384.f;
    out[(size_t)B_TOT * DIMN + 1] = s1 / 16384.f;
    out[(size_t)B_TOT * DIMN + 2] = s2 / 16384.f;
  }
}

extern "C" void kernel_launch(void* const* d_in, const int* in_sizes, int n_in,
                              void* d_out, int out_size, void* d_ws, size_t ws_size,
                              hipStream_t stream) {
  const float *x = nullptr, *wenc = nullptr, *benc = nullptr, *phase = nullptr,
              *wdec = nullptr, *bdec = nullptr, *dis = nullptr;
  for (int i = 0; i < n_in; i++) {
    switch (in_sizes[i]) {
      case 67108864: x = (const float*)d_in[i]; break;      // 16384*4096
      case 65536:    wenc = (const float*)d_in[i]; break;   // 16*4096
      case 16:       benc = (const float*)d_in[i]; break;
      case 8:        phase = (const float*)d_in[i]; break;
      case 32768:    wdec = (const float*)d_in[i]; break;   // 4096*8
      case 4096:     bdec = (const float*)d_in[i]; break;
      case 3:        dis = (const float*)d_in[i]; break;
      default: break;
    }
  }

  float* ws = (float*)d_ws;
  float* absamp = ws + ABS_OFF;
  float* bsum   = ws + MET_OFF;
  float* out = (float*)d_out;

  hipLaunchKernelGGL(k_enc, dim3(256), dim3(512), 0, stream,
                     x, wenc, benc, phase, dis, absamp, bsum);
  hipLaunchKernelGGL(k_out, dim3(256, 4), dim3(256), 0, stream,
                     absamp, wdec, bdec, out);
  hipLaunchKernelGGL(k_final, dim3(1), dim3(64), 0, stream, bsum, out);
}

// Round 12
// 180.756 us; speedup vs baseline: 1.3880x; 1.0932x over previous
//
#include <hip/hip_runtime.h>

#define B_TOT 16384
#define DIMN  4096
#define EPSF  1e-10f

#define RS   64     // rows per block
#define CH   128    // cols per chunk
#define NCH  32     // chunks
#define XS   132    // LDS row stride (pad 4)

// lds float offsets
#define XT0  0
#define XT1  (RS * XS)                   // 8448
#define WT0  (2 * RS * XS)               // 16896
#define WT1  (2 * RS * XS + 16 * XS)     // 19008
#define LDS_TOT (2 * RS * XS + 2 * 16 * XS)   // 21120 floats = 84.5 KB
// reuse after GEMM: partials [0..8192), encL at 8704 (64*17), absL at 10000 (64*8)

__device__ __forceinline__ void normalize8(float* rr, float* ii) {
  float n2 = 0.f;
#pragma unroll
  for (int q = 0; q < 8; q++) n2 += rr[q] * rr[q] + ii[q] * ii[q];
  float n = sqrtf(n2);
  if (n < EPSF) {
#pragma unroll
    for (int q = 0; q < 8; q++) { rr[q] = 0.f; ii[q] = 0.f; }
    rr[0] = 1.f;
  } else {
    float inv = 1.f / n;
#pragma unroll
    for (int q = 0; q < 8; q++) { rr[q] *= inv; ii[q] *= inv; }
  }
}

#define DOT4(a, wA, p)                                                     \
  fmaf((a).x, (wA).x, fmaf((a).y, (wA).y, fmaf((a).z, (wA).z,              \
  fmaf((a).w, (wA).w, (p)))))

// Fused: enc GEMM (4x4 outer product, x+W in LDS, 128-col dbuf chunks)
// + evolve + metrics + decode. 256 blocks x 512 thr (8 waves).
// Wave wid owns K-cols [wid*16, wid*16+16) per chunk (4 s-steps of 4).
// Lane: rho=l&15 -> rows 4rho..+3; phi=l>>4 -> feats 4phi..+3. acc[4][4].
__global__ __launch_bounds__(512) void k_encdec(
    const float* __restrict__ x, const float* __restrict__ wenc,
    const float* __restrict__ benc, const float* __restrict__ phase,
    const float* __restrict__ disorder, const float* __restrict__ wdec,
    const float* __restrict__ bdec, float* __restrict__ out,
    float* __restrict__ blocksum) {
  __shared__ float lds[LDS_TOT];

  const int t = threadIdx.x;            // 0..511
  const int l = t & 63;
  const int wid = t >> 6;               // wave 0..7 = K-sixteenth group
  const int r0 = blockIdx.x * RS;
  const int rho = l & 15;
  const int phi = l >> 4;

  float acc[4][4];
#pragma unroll
  for (int r = 0; r < 4; r++)
#pragma unroll
    for (int f = 0; f < 4; f++) acc[r][f] = 0.f;

  // staging map: all 512 threads
  const int sr = t >> 5;                // 0..15
  const int sc = (t & 31) * 4;          // 0..124
  const float* __restrict__ xp0 = x + (size_t)(r0 + sr) * DIMN + sc;
  const float* __restrict__ xp1 = x + (size_t)(r0 + 16 + sr) * DIMN + sc;
  const float* __restrict__ xp2 = x + (size_t)(r0 + 32 + sr) * DIMN + sc;
  const float* __restrict__ xp3 = x + (size_t)(r0 + 48 + sr) * DIMN + sc;
  const float* __restrict__ wp  = wenc + (size_t)sr * DIMN + sc;

  // prologue: load + stage chunk 0 into buf0
  float4 xg0 = *reinterpret_cast<const float4*>(xp0);
  float4 xg1 = *reinterpret_cast<const float4*>(xp1);
  float4 xg2 = *reinterpret_cast<const float4*>(xp2);
  float4 xg3 = *reinterpret_cast<const float4*>(xp3);
  float4 wg  = *reinterpret_cast<const float4*>(wp);
  *reinterpret_cast<float4*>(&lds[XT0 + (sr)      * XS + sc]) = xg0;
  *reinterpret_cast<float4*>(&lds[XT0 + (16 + sr) * XS + sc]) = xg1;
  *reinterpret_cast<float4*>(&lds[XT0 + (32 + sr) * XS + sc]) = xg2;
  *reinterpret_cast<float4*>(&lds[XT0 + (48 + sr) * XS + sc]) = xg3;
  *reinterpret_cast<float4*>(&lds[WT0 + sr * XS + sc]) = wg;

  for (int c = 0; c < NCH; ++c) {
    const int cur = c & 1;
    __syncthreads();                     // buf[cur] staged, prev compute done
    if (c + 1 < NCH) {                   // issue next-chunk loads
      const size_t co = (size_t)(c + 1) * CH;
      xg0 = *reinterpret_cast<const float4*>(xp0 + co);
      xg1 = *reinterpret_cast<const float4*>(xp1 + co);
      xg2 = *reinterpret_cast<const float4*>(xp2 + co);
      xg3 = *reinterpret_cast<const float4*>(xp3 + co);
      wg  = *reinterpret_cast<const float4*>(wp  + co);
    }
    const float* __restrict__ xb = &lds[cur ? XT1 : XT0];
    const float* __restrict__ wb = &lds[cur ? WT1 : WT0];
#pragma unroll
    for (int s = 0; s < 4; ++s) {
      const int col = wid * 16 + s * 4;
      float4 xr0 = *reinterpret_cast<const float4*>(&xb[(4 * rho + 0) * XS + col]);
      float4 xr1 = *reinterpret_cast<const float4*>(&xb[(4 * rho + 1) * XS + col]);
      float4 xr2 = *reinterpret_cast<const float4*>(&xb[(4 * rho + 2) * XS + col]);
      float4 xr3 = *reinterpret_cast<const float4*>(&xb[(4 * rho + 3) * XS + col]);
      float4 wf0 = *reinterpret_cast<const float4*>(&wb[(4 * phi + 0) * XS + col]);
      float4 wf1 = *reinterpret_cast<const float4*>(&wb[(4 * phi + 1) * XS + col]);
      float4 wf2 = *reinterpret_cast<const float4*>(&wb[(4 * phi + 2) * XS + col]);
      float4 wf3 = *reinterpret_cast<const float4*>(&wb[(4 * phi + 3) * XS + col]);
      acc[0][0] = DOT4(xr0, wf0, acc[0][0]);
      acc[0][1] = DOT4(xr0, wf1, acc[0][1]);
      acc[0][2] = DOT4(xr0, wf2, acc[0][2]);
      acc[0][3] = DOT4(xr0, wf3, acc[0][3]);
      acc[1][0] = DOT4(xr1, wf0, acc[1][0]);
      acc[1][1] = DOT4(xr1, wf1, acc[1][1]);
      acc[1][2] = DOT4(xr1, wf2, acc[1][2]);
      acc[1][3] = DOT4(xr1, wf3, acc[1][3]);
      acc[2][0] = DOT4(xr2, wf0, acc[2][0]);
      acc[2][1] = DOT4(xr2, wf1, acc[2][1]);
      acc[2][2] = DOT4(xr2, wf2, acc[2][2]);
      acc[2][3] = DOT4(xr2, wf3, acc[2][3]);
      acc[3][0] = DOT4(xr3, wf0, acc[3][0]);
      acc[3][1] = DOT4(xr3, wf1, acc[3][1]);
      acc[3][2] = DOT4(xr3, wf2, acc[3][2]);
      acc[3][3] = DOT4(xr3, wf3, acc[3][3]);
    }
    if (c + 1 < NCH) {                   // write prefetched regs -> other buf
      float* xo = &lds[cur ? XT0 : XT1];
      float* wo = &lds[cur ? WT0 : WT1];
      *reinterpret_cast<float4*>(&xo[(sr)      * XS + sc]) = xg0;
      *reinterpret_cast<float4*>(&xo[(16 + sr) * XS + sc]) = xg1;
      *reinterpret_cast<float4*>(&xo[(32 + sr) * XS + sc]) = xg2;
      *reinterpret_cast<float4*>(&xo[(48 + sr) * XS + sc]) = xg3;
      *reinterpret_cast<float4*>(&wo[sr * XS + sc]) = wg;
    }
  }
  __syncthreads();                       // GEMM LDS reads done; reuse lds

  // partials: lds[(row*16+feat)*8 + wid]
#pragma unroll
  for (int r = 0; r < 4; ++r)
#pragma unroll
    for (int f = 0; f < 4; ++f)
      lds[(((4 * rho + r) * 16) + (4 * phi + f)) * 8 + wid] = acc[r][f];
  __syncthreads();

  // reduce 8 K-partials -> encL[row*17+feat] at lds+8704
  float* const encL = lds + 8704;
  float* const absL = lds + 10000;
  {
    const int o0 = t * 2, o1 = t * 2 + 1;
    float4 a0 = *reinterpret_cast<const float4*>(&lds[o0 * 8]);
    float4 b0 = *reinterpret_cast<const float4*>(&lds[o0 * 8 + 4]);
    float4 a1 = *reinterpret_cast<const float4*>(&lds[o1 * 8]);
    float4 b1 = *reinterpret_cast<const float4*>(&lds[o1 * 8 + 4]);
    float s0 = ((a0.x + a0.y) + (a0.z + a0.w)) + ((b0.x + b0.y) + (b0.z + b0.w));
    float s1 = ((a1.x + a1.y) + (a1.z + a1.w)) + ((b1.x + b1.y) + (b1.z + b1.w));
    encL[(o0 >> 4) * 17 + (o0 & 15)] = s0;
    encL[(o1 >> 4) * 17 + (o1 & 15)] = s1;
  }
  __syncthreads();

  if (t < 64) {                          // wave 0: one thread per row
    const int r = r0 + t;
    float e[16];
#pragma unroll
    for (int k = 0; k < 16; k++) e[k] = tanhf(encL[t * 17 + k] + benc[k]);

    float re[8], im[8];
#pragma unroll
    for (int q = 0; q < 8; q++) {
      float ph = 0.1f * phase[q];
      float cc = cosf(ph), ss = sinf(ph);
      re[q] = e[q] * cc - e[8 + q] * ss + 0.017677669529663688f;  // +0.05/sqrt(8)
      im[q] = e[q] * ss + e[8 + q] * cc;
    }
    normalize8(re, im);

    float dd0 = disorder[0], dd1 = disorder[1], dd2 = disorder[2];
    float hz[8];
#pragma unroll
    for (int i = 0; i < 8; i++)
      hz[i] = ((i & 4) ? -dd0 : dd0) + ((i & 2) ? -dd1 : dd1) + ((i & 1) ? -dd2 : dd2);

#pragma unroll
    for (int step = 0; step < 2; step++) {
      float tt = 0.02f * (float)r + 0.01f * (float)step;
      float drive = 0.5f + 0.2f * sinf(1.61803398874989485f * tt);
      float nr[8], ni[8];
#pragma unroll
      for (int j = 0; j < 8; j++) {
        float hr = drive * (re[j ^ 1] + re[j ^ 2] + re[j ^ 4]) + hz[j] * re[j];
        float hi = drive * (im[j ^ 1] + im[j ^ 2] + im[j ^ 4]) + hz[j] * im[j];
        nr[j] = re[j] + 1e-4f * hi;      // amps - 1j*1e-4*Ha
        ni[j] = im[j] - 1e-4f * hr;
      }
      normalize8(nr, ni);
#pragma unroll
      for (int j = 0; j < 8; j++) { re[j] = nr[j]; im[j] = ni[j]; }
    }

    float tr = 0.f, s2 = 0.f;
#pragma unroll
    for (int q = 0; q < 8; q++) {
      float a2 = re[q] * re[q] + im[q] * im[q];
      tr += a2; s2 += a2 * a2;
      absL[t * 8 + q] = sqrtf(a2);
    }
    float trp = tr + EPSF;
    float purity = tr * tr / (trp * trp);
    float coh = sqrtf(fmaxf(tr * tr - s2, 0.f)) / trp;
    float lam = fminf(fmaxf(tr / trp, EPSF), 1.f);   // rho rank-1
    float denom = lam + 8.f * EPSF;
    float e1 = lam / denom, er = EPSF / denom;
    float ent = -(e1 * log2f(e1 + EPSF) + 7.f * er * log2f(er + EPSF));

    float sp = purity, sc2 = coh, sh = ent;
#pragma unroll
    for (int off = 32; off > 0; off >>= 1) {
      sp += __shfl_xor(sp, off);
      sc2 += __shfl_xor(sc2, off);
      sh += __shfl_xor(sh, off);
    }
    if (t == 0) {
      blocksum[blockIdx.x * 3 + 0] = sp;
      blocksum[blockIdx.x * 3 + 1] = sc2;
      blocksum[blockIdx.x * 3 + 2] = sh;
    }
  }
  __syncthreads();                       // absL ready

  // decode: 64 rows x 4096 cols; wdec reg-cached (L2), coalesced f4 stores
#pragma unroll
  for (int g = 0; g < 2; ++g) {
    const int c4 = g * 2048 + t * 4;
    float wd[4][8];
#pragma unroll
    for (int j = 0; j < 4; ++j) {
      float4 a = *reinterpret_cast<const float4*>(wdec + (size_t)(c4 + j) * 8);
      float4 b = *reinterpret_cast<const float4*>(wdec + (size_t)(c4 + j) * 8 + 4);
      wd[j][0] = a.x; wd[j][1] = a.y; wd[j][2] = a.z; wd[j][3] = a.w;
      wd[j][4] = b.x; wd[j][5] = b.y; wd[j][6] = b.z; wd[j][7] = b.w;
    }
    float4 bd = *reinterpret_cast<const float4*>(bdec + c4);
    for (int r = 0; r < RS; ++r) {
      float4 a0 = *reinterpret_cast<const float4*>(&absL[r * 8]);      // broadcast
      float4 a1 = *reinterpret_cast<const float4*>(&absL[r * 8 + 4]);
      float aq[8] = {a0.x, a0.y, a0.z, a0.w, a1.x, a1.y, a1.z, a1.w};
      float o0 = bd.x, o1 = bd.y, o2 = bd.z, o3 = bd.w;
#pragma unroll
      for (int q = 0; q < 8; ++q) {
        o0 = fmaf(aq[q], wd[0][q], o0);
        o1 = fmaf(aq[q], wd[1][q], o1);
        o2 = fmaf(aq[q], wd[2][q], o2);
        o3 = fmaf(aq[q], wd[3][q], o3);
      }
      *reinterpret_cast<float4*>(out + (size_t)(r0 + r) * DIMN + c4) =
          make_float4(o0, o1, o2, o3);
    }
  }
}

// finalize metric means (256 block partials)
__global__ void k_final(const float* __restrict__ blocksum,
                        float* __restrict__ out) {
  const int t = threadIdx.x;
  float s0 = 0.f, s1 = 0.f, s2 = 0.f;
  for (int b = t; b < 256; b += 64) {
    s0 += blocksum[b * 3 + 0];
    s1 += blocksum[b * 3 + 1];
    s2 += blocksum[b * 3 + 2];
  }
#pragma unroll
  for (int off = 32; off > 0; off >>= 1) {
    s0 += __shfl_down(s0, off);
    s1 += __shfl_down(s1, off);
    s2 += __shfl_down(s2, off);
  }
  if (t == 0) {
    out[(size_t)B_TOT * DIMN + 0] = s0 / 16384.f;
    out[(size_t)B_TOT * DIMN + 1] = s1 / 16384.f;
    out[(size_t)B_TOT * DIMN + 2] = s2 / 16384.f;
  }
}

extern "C" void kernel_launch(void* const* d_in, const int* in_sizes, int n_in,
                              void* d_out, int out_size, void* d_ws, size_t ws_size,
                              hipStream_t stream) {
  const float *x = nullptr, *wenc = nullptr, *benc = nullptr, *phase = nullptr,
              *wdec = nullptr, *bdec = nullptr, *dis = nullptr;
  for (int i = 0; i < n_in; i++) {
    switch (in_sizes[i]) {
      case 67108864: x = (const float*)d_in[i]; break;      // 16384*4096
      case 65536:    wenc = (const float*)d_in[i]; break;   // 16*4096
      case 16:       benc = (const float*)d_in[i]; break;
      case 8:        phase = (const float*)d_in[i]; break;
      case 32768:    wdec = (const float*)d_in[i]; break;   // 4096*8
      case 4096:     bdec = (const float*)d_in[i]; break;
      case 3:        dis = (const float*)d_in[i]; break;
      default: break;
    }
  }

  float* bsum = (float*)d_ws;                  // 256*3 floats
  float* out = (float*)d_out;

  hipLaunchKernelGGL(k_encdec, dim3(256), dim3(512), 0, stream,
                     x, wenc, benc, phase, dis, wdec, bdec, out, bsum);
  hipLaunchKernelGGL(k_final, dim3(1), dim3(64), 0, stream, bsum, out);
}

// Round 13
// 171.727 us; speedup vs baseline: 1.4610x; 1.0526x over previous
//
#include <hip/hip_runtime.h>

#define B_TOT 16384
#define DIMN  4096
#define EPSF  1e-10f

#define RS   64     // rows per block
#define CH   128    // cols per chunk
#define NCH  32     // chunks
#define XS   128    // LDS row stride (swizzled, no pad)

// lds float offsets
#define XT0  0
#define XT1  (RS * XS)                   // 8192
#define WT0  (2 * RS * XS)               // 16384
#define WT1  (WT0 + 16 * XS)             // 18432
#define LDS_TOT (WT0 + 2 * 16 * XS)      // 20480 floats = 80 KB
// post-GEMM reuse: partials (float4) in [0..9464); encL at 16384 (64*20); absL at 17664 (64*8)

__device__ __forceinline__ void normalize8(float* rr, float* ii) {
  float n2 = 0.f;
#pragma unroll
  for (int q = 0; q < 8; q++) n2 += rr[q] * rr[q] + ii[q] * ii[q];
  float n = sqrtf(n2);
  if (n < EPSF) {
#pragma unroll
    for (int q = 0; q < 8; q++) { rr[q] = 0.f; ii[q] = 0.f; }
    rr[0] = 1.f;
  } else {
    float inv = 1.f / n;
#pragma unroll
    for (int q = 0; q < 8; q++) { rr[q] *= inv; ii[q] *= inv; }
  }
}

#define DOT4(a, wA, p)                                                     \
  fmaf((a).x, (wA).x, fmaf((a).y, (wA).y, fmaf((a).z, (wA).z,              \
  fmaf((a).w, (wA).w, (p)))))

// Fused: enc GEMM (4x4 outer product, swizzled LDS) + evolve + metrics + decode.
// 256 blocks x 512 thr (8 waves). Wave wid = K-cols [wid*16,+16) per chunk.
// Lane: rho=l&15 -> rows 4rho..+3; phi=l>>4 -> feats 4phi..+3. acc[4][4].
// Swizzle: col4' = col4 ^ ((row>>2)&7)  (both store and load sides).
__global__ __launch_bounds__(512) void k_encdec(
    const float* __restrict__ x, const float* __restrict__ wenc,
    const float* __restrict__ benc, const float* __restrict__ phase,
    const float* __restrict__ disorder, const float* __restrict__ wdec,
    const float* __restrict__ bdec, float* __restrict__ out,
    float* __restrict__ blocksum) {
  __shared__ float lds[LDS_TOT];

  const int t = threadIdx.x;            // 0..511
  const int l = t & 63;
  const int wid = t >> 6;               // wave 0..7 = K-sixteenth group
  const int r0 = blockIdx.x * RS;
  const int rho = l & 15;
  const int phi = l >> 4;

  float acc[4][4];
#pragma unroll
  for (int r = 0; r < 4; r++)
#pragma unroll
    for (int f = 0; f < 4; f++) acc[r][f] = 0.f;

  // staging map: thread t stages rows {sr,16+sr,32+sr,48+sr} of x + row sr of W
  const int sr = t >> 5;                // 0..15
  const int sc4 = t & 31;               // col4 0..31
  const float* __restrict__ xp0 = x + (size_t)(r0 + sr) * DIMN + sc4 * 4;
  const float* __restrict__ xp1 = x + (size_t)(r0 + 16 + sr) * DIMN + sc4 * 4;
  const float* __restrict__ xp2 = x + (size_t)(r0 + 32 + sr) * DIMN + sc4 * 4;
  const float* __restrict__ xp3 = x + (size_t)(r0 + 48 + sr) * DIMN + sc4 * 4;
  const float* __restrict__ wp  = wenc + (size_t)sr * DIMN + sc4 * 4;
  // swizzled LDS staging offsets (constant per thread)
  const int xo0 = (sr)      * XS + ((sc4 ^ (((sr)      >> 2) & 7)) << 2);
  const int xo1 = (16 + sr) * XS + ((sc4 ^ (((16 + sr) >> 2) & 7)) << 2);
  const int xo2 = (32 + sr) * XS + ((sc4 ^ (((32 + sr) >> 2) & 7)) << 2);
  const int xo3 = (48 + sr) * XS + ((sc4 ^ (((48 + sr) >> 2) & 7)) << 2);
  const int wo_ = sr * XS + ((sc4 ^ ((sr >> 2) & 7)) << 2);

  // prologue: load + stage chunk 0 into buf0
  float4 xg0 = *reinterpret_cast<const float4*>(xp0);
  float4 xg1 = *reinterpret_cast<const float4*>(xp1);
  float4 xg2 = *reinterpret_cast<const float4*>(xp2);
  float4 xg3 = *reinterpret_cast<const float4*>(xp3);
  float4 wg  = *reinterpret_cast<const float4*>(wp);
  *reinterpret_cast<float4*>(&lds[XT0 + xo0]) = xg0;
  *reinterpret_cast<float4*>(&lds[XT0 + xo1]) = xg1;
  *reinterpret_cast<float4*>(&lds[XT0 + xo2]) = xg2;
  *reinterpret_cast<float4*>(&lds[XT0 + xo3]) = xg3;
  *reinterpret_cast<float4*>(&lds[WT0 + wo_]) = wg;

  for (int c = 0; c < NCH; ++c) {
    const int cur = c & 1;
    __syncthreads();                     // buf[cur] staged, prev compute done
    if (c + 1 < NCH) {                   // issue next-chunk loads
      const size_t co = (size_t)(c + 1) * CH;
      xg0 = *reinterpret_cast<const float4*>(xp0 + co);
      xg1 = *reinterpret_cast<const float4*>(xp1 + co);
      xg2 = *reinterpret_cast<const float4*>(xp2 + co);
      xg3 = *reinterpret_cast<const float4*>(xp3 + co);
      wg  = *reinterpret_cast<const float4*>(wp  + co);
    }
    const float* __restrict__ xb = &lds[cur ? XT1 : XT0];
    const float* __restrict__ wb = &lds[cur ? WT1 : WT0];
#pragma unroll
    for (int s = 0; s < 4; ++s) {
      const int c4 = wid * 4 + s;
      const int xc = (c4 ^ (rho & 7)) << 2;    // x swizzle: (row>>2)&7 = rho&7
      const int wc0 = (c4 ^ 0) << 2;           // w swizzle: (row>>2)&7 = phi
      const int wc1 = (c4 ^ 1) << 2;
      const int wc2 = (c4 ^ 2) << 2;
      const int wc3 = (c4 ^ 3) << 2;
      float4 xr0 = *reinterpret_cast<const float4*>(&xb[(4 * rho + 0) * XS + xc]);
      float4 xr1 = *reinterpret_cast<const float4*>(&xb[(4 * rho + 1) * XS + xc]);
      float4 xr2 = *reinterpret_cast<const float4*>(&xb[(4 * rho + 2) * XS + xc]);
      float4 xr3 = *reinterpret_cast<const float4*>(&xb[(4 * rho + 3) * XS + xc]);
      const int wsw = (phi == 0) ? wc0 : (phi == 1) ? wc1 : (phi == 2) ? wc2 : wc3;
      float4 wf0 = *reinterpret_cast<const float4*>(&wb[(4 * phi + 0) * XS + wsw]);
      float4 wf1 = *reinterpret_cast<const float4*>(&wb[(4 * phi + 1) * XS + wsw]);
      float4 wf2 = *reinterpret_cast<const float4*>(&wb[(4 * phi + 2) * XS + wsw]);
      float4 wf3 = *reinterpret_cast<const float4*>(&wb[(4 * phi + 3) * XS + wsw]);
      acc[0][0] = DOT4(xr0, wf0, acc[0][0]);
      acc[0][1] = DOT4(xr0, wf1, acc[0][1]);
      acc[0][2] = DOT4(xr0, wf2, acc[0][2]);
      acc[0][3] = DOT4(xr0, wf3, acc[0][3]);
      acc[1][0] = DOT4(xr1, wf0, acc[1][0]);
      acc[1][1] = DOT4(xr1, wf1, acc[1][1]);
      acc[1][2] = DOT4(xr1, wf2, acc[1][2]);
      acc[1][3] = DOT4(xr1, wf3, acc[1][3]);
      acc[2][0] = DOT4(xr2, wf0, acc[2][0]);
      acc[2][1] = DOT4(xr2, wf1, acc[2][1]);
      acc[2][2] = DOT4(xr2, wf2, acc[2][2]);
      acc[2][3] = DOT4(xr2, wf3, acc[2][3]);
      acc[3][0] = DOT4(xr3, wf0, acc[3][0]);
      acc[3][1] = DOT4(xr3, wf1, acc[3][1]);
      acc[3][2] = DOT4(xr3, wf2, acc[3][2]);
      acc[3][3] = DOT4(xr3, wf3, acc[3][3]);
    }
    if (c + 1 < NCH) {                   // write prefetched regs -> other buf
      float* xo = &lds[cur ? XT0 : XT1];
      float* wo = &lds[cur ? WT0 : WT1];
      *reinterpret_cast<float4*>(&xo[xo0]) = xg0;
      *reinterpret_cast<float4*>(&xo[xo1]) = xg1;
      *reinterpret_cast<float4*>(&xo[xo2]) = xg2;
      *reinterpret_cast<float4*>(&xo[xo3]) = xg3;
      *reinterpret_cast<float4*>(&wo[wo_]) = wg;
    }
  }
  __syncthreads();                       // GEMM LDS reads done; reuse lds

  // partials as float4: lds4[row*37 + phi*9 + wid] = acc[r][0..3]
  float4* const lds4 = reinterpret_cast<float4*>(lds);
#pragma unroll
  for (int r = 0; r < 4; ++r)
    lds4[(4 * rho + r) * 37 + phi * 9 + wid] =
        make_float4(acc[r][0], acc[r][1], acc[r][2], acc[r][3]);
  __syncthreads();

  // reduce 8 K-partials -> encL[row*20 + feat] at lds+16384
  float* const encL = lds + 16384;
  float* const absL = lds + 17664;
  if (t < 256) {
    const int row = t >> 2, ph = t & 3;
    float4 s = lds4[row * 37 + ph * 9 + 0];
#pragma unroll
    for (int wsum = 1; wsum < 8; ++wsum) {
      float4 v = lds4[row * 37 + ph * 9 + wsum];
      s.x += v.x; s.y += v.y; s.z += v.z; s.w += v.w;
    }
    encL[row * 20 + ph * 4 + 0] = s.x;
    encL[row * 20 + ph * 4 + 1] = s.y;
    encL[row * 20 + ph * 4 + 2] = s.z;
    encL[row * 20 + ph * 4 + 3] = s.w;
  }
  __syncthreads();

  if (t < 64) {                          // wave 0: one thread per row
    const int r = r0 + t;
    float e[16];
#pragma unroll
    for (int k = 0; k < 16; k++) e[k] = tanhf(encL[t * 20 + k] + benc[k]);

    float re[8], im[8];
#pragma unroll
    for (int q = 0; q < 8; q++) {
      float ph = 0.1f * phase[q];
      float cc = cosf(ph), ss = sinf(ph);
      re[q] = e[q] * cc - e[8 + q] * ss + 0.017677669529663688f;  // +0.05/sqrt(8)
      im[q] = e[q] * ss + e[8 + q] * cc;
    }
    normalize8(re, im);

    float dd0 = disorder[0], dd1 = disorder[1], dd2 = disorder[2];
    float hz[8];
#pragma unroll
    for (int i = 0; i < 8; i++)
      hz[i] = ((i & 4) ? -dd0 : dd0) + ((i & 2) ? -dd1 : dd1) + ((i & 1) ? -dd2 : dd2);

#pragma unroll
    for (int step = 0; step < 2; step++) {
      float tt = 0.02f * (float)r + 0.01f * (float)step;
      float drive = 0.5f + 0.2f * sinf(1.61803398874989485f * tt);
      float nr[8], ni[8];
#pragma unroll
      for (int j = 0; j < 8; j++) {
        float hr = drive * (re[j ^ 1] + re[j ^ 2] + re[j ^ 4]) + hz[j] * re[j];
        float hi = drive * (im[j ^ 1] + im[j ^ 2] + im[j ^ 4]) + hz[j] * im[j];
        nr[j] = re[j] + 1e-4f * hi;      // amps - 1j*1e-4*Ha
        ni[j] = im[j] - 1e-4f * hr;
      }
      normalize8(nr, ni);
#pragma unroll
      for (int j = 0; j < 8; j++) { re[j] = nr[j]; im[j] = ni[j]; }
    }

    float tr = 0.f, s2 = 0.f;
#pragma unroll
    for (int q = 0; q < 8; q++) {
      float a2 = re[q] * re[q] + im[q] * im[q];
      tr += a2; s2 += a2 * a2;
      absL[t * 8 + q] = sqrtf(a2);
    }
    float trp = tr + EPSF;
    float purity = tr * tr / (trp * trp);
    float coh = sqrtf(fmaxf(tr * tr - s2, 0.f)) / trp;
    float lam = fminf(fmaxf(tr / trp, EPSF), 1.f);   // rho rank-1
    float denom = lam + 8.f * EPSF;
    float e1 = lam / denom, er = EPSF / denom;
    float ent = -(e1 * log2f(e1 + EPSF) + 7.f * er * log2f(er + EPSF));

    float sp = purity, sc2 = coh, sh = ent;
#pragma unroll
    for (int off = 32; off > 0; off >>= 1) {
      sp += __shfl_xor(sp, off);
      sc2 += __shfl_xor(sc2, off);
      sh += __shfl_xor(sh, off);
    }
    if (t == 0) {
      blocksum[blockIdx.x * 3 + 0] = sp;
      blocksum[blockIdx.x * 3 + 1] = sc2;
      blocksum[blockIdx.x * 3 + 2] = sh;
    }
  }
  __syncthreads();                       // absL ready

  // decode: 64 rows x 4096 cols; wdec reg-cached (L2), coalesced f4 stores
#pragma unroll
  for (int g = 0; g < 2; ++g) {
    const int c4 = g * 2048 + t * 4;
    float wd[4][8];
#pragma unroll
    for (int j = 0; j < 4; ++j) {
      float4 a = *reinterpret_cast<const float4*>(wdec + (size_t)(c4 + j) * 8);
      float4 b = *reinterpret_cast<const float4*>(wdec + (size_t)(c4 + j) * 8 + 4);
      wd[j][0] = a.x; wd[j][1] = a.y; wd[j][2] = a.z; wd[j][3] = a.w;
      wd[j][4] = b.x; wd[j][5] = b.y; wd[j][6] = b.z; wd[j][7] = b.w;
    }
    float4 bd = *reinterpret_cast<const float4*>(bdec + c4);
    for (int r = 0; r < RS; ++r) {
      float4 a0 = *reinterpret_cast<const float4*>(&absL[r * 8]);      // broadcast
      float4 a1 = *reinterpret_cast<const float4*>(&absL[r * 8 + 4]);
      float aq[8] = {a0.x, a0.y, a0.z, a0.w, a1.x, a1.y, a1.z, a1.w};
      float o0 = bd.x, o1 = bd.y, o2 = bd.z, o3 = bd.w;
#pragma unroll
      for (int q = 0; q < 8; ++q) {
        o0 = fmaf(aq[q], wd[0][q], o0);
        o1 = fmaf(aq[q], wd[1][q], o1);
        o2 = fmaf(aq[q], wd[2][q], o2);
        o3 = fmaf(aq[q], wd[3][q], o3);
      }
      *reinterpret_cast<float4*>(out + (size_t)(r0 + r) * DIMN + c4) =
          make_float4(o0, o1, o2, o3);
    }
  }
}

// finalize metric means (256 block partials)
__global__ void k_final(const float* __restrict__ blocksum,
                        float* __restrict__ out) {
  const int t = threadIdx.x;
  float s0 = 0.f, s1 = 0.f, s2 = 0.f;
  for (int b = t; b < 256; b += 64) {
    s0 += blocksum[b * 3 + 0];
    s1 += blocksum[b * 3 + 1];
    s2 += blocksum[b * 3 + 2];
  }
#pragma unroll
  for (int off = 32; off > 0; off >>= 1) {
    s0 += __shfl_down(s0, off);
    s1 += __shfl_down(s1, off);
    s2 += __shfl_down(s2, off);
  }
  if (t == 0) {
    out[(size_t)B_TOT * DIMN + 0] = s0 / 16384.f;
    out[(size_t)B_TOT * DIMN + 1] = s1 / 16384.f;
    out[(size_t)B_TOT * DIMN + 2] = s2 / 16384.f;
  }
}

extern "C" void kernel_launch(void* const* d_in, const int* in_sizes, int n_in,
                              void* d_out, int out_size, void* d_ws, size_t ws_size,
                              hipStream_t stream) {
  const float *x = nullptr, *wenc = nullptr, *benc = nullptr, *phase = nullptr,
              *wdec = nullptr, *bdec = nullptr, *dis = nullptr;
  for (int i = 0; i < n_in; i++) {
    switch (in_sizes[i]) {
      case 67108864: x = (const float*)d_in[i]; break;      // 16384*4096
      case 65536:    wenc = (const float*)d_in[i]; break;   // 16*4096
      case 16:       benc = (const float*)d_in[i]; break;
      case 8:        phase = (const float*)d_in[i]; break;
      case 32768:    wdec = (const float*)d_in[i]; break;   // 4096*8
      case 4096:     bdec = (const float*)d_in[i]; break;
      case 3:        dis = (const float*)d_in[i]; break;
      default: break;
    }
  }

  float* bsum = (float*)d_ws;                  // 256*3 floats
  float* out = (float*)d_out;

  hipLaunchKernelGGL(k_encdec, dim3(256), dim3(512), 0, stream,
                     x, wenc, benc, phase, dis, wdec, bdec, out, bsum);
  hipLaunchKernelGGL(k_final, dim3(1), dim3(64), 0, stream, bsum, out);
}